// Round 16
// baseline (256.302 us; speedup 1.0000x reference)
//
#include <hip/hip_runtime.h>
#include <stdint.h>
#include <cmath>

typedef unsigned short ushort_t;
typedef __attribute__((ext_vector_type(8))) short bf16x8;
typedef __attribute__((ext_vector_type(4))) float f32x4;
typedef __attribute__((ext_vector_type(4))) unsigned int u32x4;

#define NTOK 49
#define DIMC 192
#define NH 6
#define HD 32
#define SCALE 0.17677669529663687f
#define LOG2E 1.4426950408889634f
#define LN2   0.6931471805599453f
#define XS 200      // x/q/k/ao row stride (bf16 elems)
#define VTS 72      // vT row stride (tokens)
#define PS 72       // P row stride
#define MS 66       // mask row stride (f32)  [MODE<2 only]
#define RS 68       // rel row stride (u16)   [MODE<2 only]

// LDS carve (bytes), all 16B aligned
#define OFF_X    0          // [64][200] bf16 : x, later attn-out (ao)
#define OFF_Q    25600      // [64][200] bf16
#define OFF_K    51200      // [64][200] bf16
#define OFF_VT   76800      // [192][72] bf16
#define OFF_P    104448     // [8][16][72] bf16
#define OFF_MASK 122880     // [64][66] f32      [MODE<2]
#define OFF_RPB  139776     // [169][8] f32      [MODE<2]
#define OFF_REL  145184     // [64][68] u16      [MODE<2]
#define OFF_BQ   153888     // [576] f32
#define OFF_BP   156192     // [192] f32
#define SMEM_BYTES 156960

#define QKVW_N (576 * 192)
#define PROJW_N (192 * 192)
#define QKV_GRP (4 * 9 * 6 * 64)
#define PROJ_GRP (4 * 3 * 6 * 64)
#define WBF_BYTES ((QKVW_N + PROJW_N) * 2)
#define BIAS_FLOATS (64 * 6 * 4 * 4 * 4 * 16 * 4)
#define WS_NEED1 ((size_t)WBF_BYTES)
#define WS_NEED2 ((size_t)WBF_BYTES + (size_t)BIAS_FLOATS * 4)

__device__ __forceinline__ ushort_t f2bf(float f) {
    uint32_t x = __builtin_bit_cast(uint32_t, f);
    x += 0x7fffu + ((x >> 16) & 1u);   // RNE
    return (ushort_t)(x >> 16);
}
__device__ __forceinline__ uint32_t cvtpk(float lo, float hi) {   // packed RNE f32->bf16 pair
    uint32_t r;
    asm("v_cvt_pk_bf16_f32 %0, %1, %2" : "=v"(r) : "v"(lo), "v"(hi));
    return r;
}

__device__ __forceinline__ bf16x8 cvt8(const float* p) {
    f32x4 a = *(const f32x4*)p;
    f32x4 b = *(const f32x4*)(p + 4);
    bf16x8 r;
    r[0] = (short)f2bf(a[0]); r[1] = (short)f2bf(a[1]);
    r[2] = (short)f2bf(a[2]); r[3] = (short)f2bf(a[3]);
    r[4] = (short)f2bf(b[0]); r[5] = (short)f2bf(b[1]);
    r[6] = (short)f2bf(b[2]); r[7] = (short)f2bf(b[3]);
    return r;
}

// ---- pre-pass 1: f32 weights -> bf16, MFMA-fragment-swizzled ----
// q-cols pre-scaled by SCALE*LOG2E so QK^T score is already in exp2 domain.
__global__ __launch_bounds__(256) void swz_weights_kernel(
    const float* __restrict__ qkvw, const float* __restrict__ projw,
    ushort_t* __restrict__ dst)
{
    int i = blockIdx.x * 256 + threadIdx.x;
    if (i >= QKV_GRP + PROJ_GRP) return;
    const float* src;
    float s = 1.0f;
    if (i < QKV_GRP) {
        int lane = i & 63, t = i >> 6;
        int kk = t % 6, nt = (t / 6) % 9, cq = t / 54;
        int col = cq * 144 + nt * 16 + (lane & 15);
        int k0 = kk * 32 + (lane >> 4) * 8;
        src = qkvw + col * DIMC + k0;
        if (col < 192) s = SCALE * LOG2E;       // fold 1/sqrt(hd) * log2(e)
    } else {
        int j = i - QKV_GRP;
        int lane = j & 63, t = j >> 6;
        int kk = t % 6, nt = (t / 6) % 3, cq = t / 18;
        int col = cq * 48 + nt * 16 + (lane & 15);
        int k0 = kk * 32 + (lane >> 4) * 8;
        src = projw + col * DIMC + k0;
    }
    f32x4 a = *(const f32x4*)src;
    f32x4 b = *(const f32x4*)(src + 4);
    u32x4 o;
    o[0] = (uint32_t)f2bf(a[0] * s) | ((uint32_t)f2bf(a[1] * s) << 16);
    o[1] = (uint32_t)f2bf(a[2] * s) | ((uint32_t)f2bf(a[3] * s) << 16);
    o[2] = (uint32_t)f2bf(b[0] * s) | ((uint32_t)f2bf(b[1] * s) << 16);
    o[3] = (uint32_t)f2bf(b[2] * s) | ((uint32_t)f2bf(b[3] * s) << 16);
    *(u32x4*)(dst + (size_t)i * 8) = o;
}

// ---- pre-pass 2: bias in MFMA C-fragment order, scaled by LOG2E (exp2 domain) ----
__global__ __launch_bounds__(256) void bias_kernel(
    const float* __restrict__ mask_g, const float* __restrict__ rpb_g,
    const int* __restrict__ rel_g, float* __restrict__ dst)
{
    int i = blockIdx.x * 256 + threadIdx.x;
    if (i >= BIAS_FLOATS / 4) return;
    int c = i & 15, g = (i >> 4) & 3, t = (i >> 6) & 3, wsid = (i >> 8) & 3;
    int hw = i >> 10;
    int h = hw % 6, wi = hw / 6;
    int m0 = 16 * wsid + 4 * g, n = 16 * t + c;
    f32x4 v;
    #pragma unroll
    for (int r = 0; r < 4; ++r) {
        int m = m0 + r;
        float val;
        if (n >= NTOK)      val = -30000.0f;
        else if (m >= NTOK) val = 0.0f;
        else val = mask_g[(size_t)wi * (NTOK * NTOK) + m * NTOK + n]
                 + rpb_g[(size_t)rel_g[m * NTOK + n] * NH + h];
        v[r] = val * LOG2E;
    }
    *(f32x4*)(dst + (size_t)i * 4) = v;
}

// MODE: 2 = swizzled weights + precomputed bias, 1 = swizzled weights, 0 = raw
template <int MODE>
__global__ __launch_bounds__(512, 2) void win_attn_kernel(
    const float* __restrict__ x_g,
    const float* __restrict__ mask_g,
    const float* __restrict__ rpb_g,
    const int* __restrict__ rel_g,
    const float* __restrict__ qkvw_g,
    const float* __restrict__ qkvb_g,
    const float* __restrict__ projw_g,
    const float* __restrict__ projb_g,
    const ushort_t* __restrict__ wbf_g,
    const float* __restrict__ bias_g,
    float* __restrict__ out_g)
{
    extern __shared__ char smem[];
    ushort_t* x_lds  = (ushort_t*)(smem + OFF_X);
    ushort_t* q_lds  = (ushort_t*)(smem + OFF_Q);
    ushort_t* k_lds  = (ushort_t*)(smem + OFF_K);
    ushort_t* vT     = (ushort_t*)(smem + OFF_VT);
    ushort_t* P_lds  = (ushort_t*)(smem + OFF_P);
    float*    mask_p = (float*)(smem + OFF_MASK);
    float*    rpb_l  = (float*)(smem + OFF_RPB);
    ushort_t* rel_p  = (ushort_t*)(smem + OFF_REL);
    float*    bq     = (float*)(smem + OFF_BQ);
    float*    bp     = (float*)(smem + OFF_BP);

    const int tid  = threadIdx.x;
    const int b    = blockIdx.x;
    const int wi   = b & 63;
    const int w    = tid >> 6;
    const int lane = tid & 63;
    const int g    = lane >> 4;
    const int c    = lane & 15;
    const int codd = c & 1;            // lane parity within col pair
    const int colp = c & ~1;           // even column of the pair (local)

    // ---- QKV weight ring: ISSUE BEFORE STAGE (no LDS dep; hides under stage+barrier) ----
    bf16x8 ring[4][6];
    {
        if constexpr (MODE >= 1) {
            const int cq = w & 3;
            const ushort_t* wq = wbf_g + (size_t)cq * (9 * 6 * 64 * 8);
            #pragma unroll
            for (int p = 0; p < 3; ++p)
                #pragma unroll
                for (int kk = 0; kk < 6; ++kk)
                    ring[p][kk] = *(const bf16x8*)(wq + (size_t)((p * 6 + kk) * 64 + lane) * 8);
            __builtin_amdgcn_sched_barrier(0);   // pin: issued before anything below
        }
    }

    // ---------------- stage ----------------
    {
        const float* xg = x_g + (size_t)b * (NTOK * DIMC);
        for (int i = tid; i < 64 * 24; i += 512) {
            int row = i / 24, col = (i % 24) * 8;
            u32x4 v = {0u, 0u, 0u, 0u};
            if (row < NTOK) {
                const float* src = xg + row * DIMC + col;
                f32x4 a = *(const f32x4*)src;
                f32x4 d = *(const f32x4*)(src + 4);
                v[0] = cvtpk(a[0], a[1]); v[1] = cvtpk(a[2], a[3]);
                v[2] = cvtpk(d[0], d[1]); v[3] = cvtpk(d[2], d[3]);
            }
            *(u32x4*)&x_lds[row * XS + col] = v;
        }
        if constexpr (MODE < 2) {
            const float* mw = mask_g + (size_t)wi * (NTOK * NTOK);
            for (int i = tid; i < 64 * 64; i += 512) {
                int m = i >> 6, n = i & 63;
                float f;
                if (n >= NTOK)      f = -30000.0f;
                else if (m >= NTOK) f = 0.0f;
                else                f = mw[m * NTOK + n];
                mask_p[m * MS + n] = f;
                rel_p[m * RS + n] = (m < NTOK && n < NTOK) ? (ushort_t)rel_g[m * NTOK + n]
                                                           : (ushort_t)0;
            }
            for (int i = tid; i < 169 * 6; i += 512)
                rpb_l[(i / 6) * 8 + (i % 6)] = rpb_g[i];
        }
        for (int i = tid; i < 576; i += 512) {
            float v = qkvb_g[i];
            if constexpr (MODE >= 1) { if (i < 192) v *= SCALE * LOG2E; }
            bq[i] = v;
        }
        if (tid < 192) bp[tid] = projb_g[tid];
    }
    __syncthreads();

    // ---------------- QKV GEMM: wave (mh = w>>2, cq = w&3) ----------------
    {
        const int mh = w >> 2, cq = w & 3;
        const ushort_t* wq = wbf_g + (size_t)cq * (9 * 6 * 64 * 8);

        bf16x8 ax[2][6];
        #pragma unroll
        for (int mt = 0; mt < 2; ++mt)
            #pragma unroll
            for (int kk = 0; kk < 6; ++kk)
                ax[mt][kk] = *(const bf16x8*)&x_lds[(32 * mh + 16 * mt + c) * XS + kk * 32 + g * 8];

        #pragma unroll
        for (int nt = 0; nt < 9; ++nt) {
            const int cg = 144 * cq + nt * 16 + c;
            bf16x8 bw[6];
            if constexpr (MODE >= 1) {
                if (nt + 3 < 9) {
                    #pragma unroll
                    for (int kk = 0; kk < 6; ++kk)
                        ring[(nt + 3) & 3][kk] =
                            *(const bf16x8*)(wq + (size_t)(((nt + 3) * 6 + kk) * 64 + lane) * 8);
                }
                __builtin_amdgcn_sched_barrier(0);
                #pragma unroll
                for (int kk = 0; kk < 6; ++kk) bw[kk] = ring[nt & 3][kk];
            } else {
                #pragma unroll
                for (int kk = 0; kk < 6; ++kk)
                    bw[kk] = cvt8(qkvw_g + (size_t)cg * DIMC + kk * 32 + g * 8);
            }
            const float bias = bq[cg];
            f32x4 acc[2];
            acc[0] = (f32x4){bias, bias, bias, bias};
            acc[1] = acc[0];
            #pragma unroll
            for (int kk = 0; kk < 6; ++kk)
                #pragma unroll
                for (int mt = 0; mt < 2; ++mt)
                    acc[mt] = __builtin_amdgcn_mfma_f32_16x16x32_bf16(ax[mt][kk], bw[kk], acc[mt], 0, 0, 0);

            const int seg = 144 * cq + nt * 16;
            const int cgp = (144 * cq + nt * 16 + colp);      // even col of pair (global)
            // pairwise col-merge epilogue: lanes (c, c^1) exchange; even lane stores
            // rows r0,r0+1, odd lane rows r0+2,r0+3 -- u32 stores, 2-way banks (free)
            if (seg < 192 || (seg >= 192 && seg < 384)) {     // q or k: row-major store
                ushort_t* dstb = (seg < 192) ? q_lds : k_lds;
                const int cc = (seg < 192) ? cgp : (cgp - 192);
                #pragma unroll
                for (int mt = 0; mt < 2; ++mt) {
                    uint32_t p01 = cvtpk(acc[mt][0], acc[mt][1]);
                    uint32_t p23 = cvtpk(acc[mt][2], acc[mt][3]);
                    uint32_t x01 = __shfl_xor(p01, 1);
                    uint32_t x23 = __shfl_xor(p23, 1);
                    const int r0 = 32 * mh + 16 * mt + g * 4;
                    uint32_t wa = codd ? ((x23 & 0xffffu) | (p23 << 16))
                                       : ((p01 & 0xffffu) | (x01 << 16));
                    uint32_t wb = codd ? ((x23 >> 16) | (p23 & 0xffff0000u))
                                       : ((p01 >> 16) | (x01 & 0xffff0000u));
                    const int ra = r0 + (codd ? 2 : 0);
                    *(uint32_t*)&dstb[(ra + 0) * XS + cc] = wa;
                    *(uint32_t*)&dstb[(ra + 1) * XS + cc] = wb;
                }
            } else {                    // v -> vT[h*32+dim][token] (already u32, conflict-free)
                const int cv = cg - 384;
                #pragma unroll
                for (int mt = 0; mt < 2; ++mt) {
                    uint32_t* dst = (uint32_t*)&vT[cv * VTS + 32 * mh + 16 * mt + g * 4];
                    dst[0] = cvtpk(acc[mt][0], acc[mt][1]);
                    dst[1] = cvtpk(acc[mt][2], acc[mt][3]);
                }
            }
        }
    }
    __syncthreads();

    // ---------------- attention: wave (wsid = w&3, hh = w>>2) ----------------
    bf16x8 pw[3][6];
    {
        const int wsid = w & 3, hh = w >> 2;
        ushort_t* Pw = P_lds + w * (16 * PS);
        const int mq0 = 16 * wsid + g * 4;

        if constexpr (MODE == 2) {
            // pipelined: QKT0,QKT1,SM0,QKT2,PV0,SM1,PV1,[pw],SM2,PV2
            const int h0 = hh * 3;
            f32x4 S0[4], S1[4], S2[4];
            const short oneb = (short)0x3F80;            // bf16 1.0
            bf16x8 ones8 = {oneb, oneb, oneb, oneb, oneb, oneb, oneb, oneb};

            auto QKT = [&](int h, f32x4* S) {
                bf16x8 aq = *(const bf16x8*)&q_lds[(16 * wsid + c) * XS + h * HD + g * 8];
                const float* bC = bias_g + ((size_t)((wi * 6 + h) * 4 + wsid) * 4) * 256 + lane * 4;
                __builtin_amdgcn_s_setprio(1);
                #pragma unroll
                for (int t = 0; t < 4; ++t) {
                    f32x4 Ct = *(const f32x4*)(bC + t * 256);
                    bf16x8 bk = *(const bf16x8*)&k_lds[(16 * t + c) * XS + h * HD + g * 8];
                    S[t] = __builtin_amdgcn_mfma_f32_16x16x32_bf16(aq, bk, Ct, 0, 0, 0);
                }
                __builtin_amdgcn_s_setprio(0);
            };
            // P = exp2(S); pairwise col-merge stores: even lane col-groups {0,32},
            // odd lane {16,48} -> u32 stores, banks fully spread (free)
            auto SM = [&](f32x4* S) {
                #pragma unroll
                for (int r = 0; r < 4; ++r) {
                    float e0 = exp2f(S[0][r]), e1 = exp2f(S[1][r]);
                    float e2 = exp2f(S[2][r]), e3 = exp2f(S[3][r]);
                    uint32_t p01 = cvtpk(e0, e1);   // lo: col c, hi: col 16+c
                    uint32_t p23 = cvtpk(e2, e3);   // lo: col 32+c, hi: col 48+c
                    uint32_t x01 = __shfl_xor(p01, 1);
                    uint32_t x23 = __shfl_xor(p23, 1);
                    uint32_t wa = codd ? ((x01 >> 16) | (p01 & 0xffff0000u))
                                       : ((p01 & 0xffffu) | (x01 << 16));
                    uint32_t wb = codd ? ((x23 >> 16) | (p23 & 0xffff0000u))
                                       : ((p23 & 0xffffu) | (x23 << 16));
                    const int off = codd ? 16 : 0;
                    ushort_t* pr = Pw + (g * 4 + r) * PS + off + colp;
                    *(uint32_t*)&pr[0]  = wa;
                    *(uint32_t*)&pr[32] = wb;
                }
            };
            // PV + MFMA row-sum (ones B tile): D[r][c] = rowsum for all c -> rinv in-lane
            auto PV = [&](int h) {
                f32x4 z = {0.f, 0.f, 0.f, 0.f};
                f32x4 O[2] = {z, z};
                f32x4 Osum = z;
                __builtin_amdgcn_s_setprio(1);
                #pragma unroll
                for (int ks = 0; ks < 2; ++ks) {
                    bf16x8 ap = *(const bf16x8*)&Pw[c * PS + ks * 32 + g * 8];
                    #pragma unroll
                    for (int nt = 0; nt < 2; ++nt) {
                        bf16x8 bv = *(const bf16x8*)&vT[(h * HD + nt * 16 + c) * VTS + ks * 32 + g * 8];
                        O[nt] = __builtin_amdgcn_mfma_f32_16x16x32_bf16(ap, bv, O[nt], 0, 0, 0);
                    }
                    Osum = __builtin_amdgcn_mfma_f32_16x16x32_bf16(ap, ones8, Osum, 0, 0, 0);
                }
                __builtin_amdgcn_s_setprio(0);
                #pragma unroll
                for (int r = 0; r < 4; ++r) {
                    float rinv = 1.0f / Osum[r];
                    uint32_t po = cvtpk(O[0][r] * rinv, O[1][r] * rinv);  // lo: col h32+c, hi: h32+16+c
                    uint32_t xo = __shfl_xor(po, 1);
                    uint32_t wv = codd ? ((xo >> 16) | (po & 0xffff0000u))
                                       : ((po & 0xffffu) | (xo << 16));
                    const int off = codd ? 16 : 0;
                    *(uint32_t*)&x_lds[(16 * wsid + g * 4 + r) * XS + h * HD + off + colp] = wv;
                }
            };

            QKT(h0 + 0, S0);
            QKT(h0 + 1, S1);
            SM(S0);
            QKT(h0 + 2, S2);
            PV(h0 + 0);
            SM(S1);                 // P1 write after PV0 read (program order, same wave)
            PV(h0 + 1);
            {                       // proj weights; short liveness
                const int cq4 = w & 3;
                const ushort_t* wp = wbf_g + QKVW_N + (size_t)cq4 * (3 * 6 * 64 * 8);
                #pragma unroll
                for (int nt = 0; nt < 3; ++nt)
                    #pragma unroll
                    for (int kk = 0; kk < 6; ++kk)
                        pw[nt][kk] = *(const bf16x8*)(wp + (size_t)((nt * 6 + kk) * 64 + lane) * 8);
                __builtin_amdgcn_sched_barrier(0);
            }
            SM(S2);
            PV(h0 + 2);
        } else {
            auto head = [&](int h) {
                bf16x8 aq = *(const bf16x8*)&q_lds[(16 * wsid + c) * XS + h * HD + g * 8];
                f32x4 S[4];
                #pragma unroll
                for (int t = 0; t < 4; ++t) {
                    bf16x8 bk = *(const bf16x8*)&k_lds[(16 * t + c) * XS + h * HD + g * 8];
                    f32x4 z = {0.f, 0.f, 0.f, 0.f};
                    S[t] = __builtin_amdgcn_mfma_f32_16x16x32_bf16(aq, bk, z, 0, 0, 0);
                }
                float rinv[4];
                #pragma unroll
                for (int r = 0; r < 4; ++r) {
                    const int mq = mq0 + r;
                    const float*    mrow = mask_p + mq * MS;
                    const ushort_t* rrow = rel_p + mq * RS;
                    float sv[4];
                    #pragma unroll
                    for (int t = 0; t < 4; ++t) {
                        const int n = 16 * t + c;
                        float sc = (MODE == 0) ? SCALE : LN2;
                        sv[t] = S[t][r] * sc + rpb_l[(int)rrow[n] * 8 + h] + mrow[n];
                    }
                    float vmax = fmaxf(fmaxf(sv[0], sv[1]), fmaxf(sv[2], sv[3]));
                    #pragma unroll
                    for (int xm = 1; xm < 16; xm <<= 1)
                        vmax = fmaxf(vmax, __shfl_xor(vmax, xm));
                    float sum = 0.f;
                    float ev[4];
                    #pragma unroll
                    for (int t = 0; t < 4; ++t) {
                        ev[t] = __expf(fmaxf(sv[t] - vmax, -80.0f));
                        sum += ev[t];
                    }
                    #pragma unroll
                    for (int xm = 1; xm < 16; xm <<= 1)
                        sum += __shfl_xor(sum, xm);
                    rinv[r] = 1.0f / sum;
                    uint32_t p01 = cvtpk(ev[0], ev[1]);
                    uint32_t p23 = cvtpk(ev[2], ev[3]);
                    ushort_t* pr = Pw + (g * 4 + r) * PS + c;
                    pr[0]  = (ushort_t)p01;
                    pr[16] = (ushort_t)(p01 >> 16);
                    pr[32] = (ushort_t)p23;
                    pr[48] = (ushort_t)(p23 >> 16);
                }
                f32x4 z = {0.f, 0.f, 0.f, 0.f};
                f32x4 O[2] = {z, z};
                #pragma unroll
                for (int ks = 0; ks < 2; ++ks) {
                    bf16x8 ap = *(const bf16x8*)&Pw[c * PS + ks * 32 + g * 8];
                    #pragma unroll
                    for (int nt = 0; nt < 2; ++nt) {
                        bf16x8 bv = *(const bf16x8*)&vT[(h * HD + nt * 16 + c) * VTS + ks * 32 + g * 8];
                        O[nt] = __builtin_amdgcn_mfma_f32_16x16x32_bf16(ap, bv, O[nt], 0, 0, 0);
                    }
                }
                #pragma unroll
                for (int r = 0; r < 4; ++r) {
                    uint32_t po = cvtpk(O[0][r] * rinv[r], O[1][r] * rinv[r]);
                    ushort_t* ar = x_lds + (16 * wsid + g * 4 + r) * XS + h * HD + c;
                    ar[0]  = (ushort_t)po;
                    ar[16] = (ushort_t)(po >> 16);
                }
            };
            head(hh * 3 + 0);
            head(hh * 3 + 1);
            if constexpr (MODE >= 1) {
                const int cq4 = w & 3;
                const ushort_t* wp = wbf_g + QKVW_N + (size_t)cq4 * (3 * 6 * 64 * 8);
                #pragma unroll
                for (int nt = 0; nt < 3; ++nt)
                    #pragma unroll
                    for (int kk = 0; kk < 6; ++kk)
                        pw[nt][kk] = *(const bf16x8*)(wp + (size_t)((nt * 6 + kk) * 64 + lane) * 8);
                __builtin_amdgcn_sched_barrier(0);
            }
            head(hh * 3 + 2);
        }
    }
    __syncthreads();

    // ---------------- proj GEMM -> direct f32 global store ----------------
    {
        const int mh = w >> 2, cq4 = w & 3;
        bf16x8 aa[2][6];
        #pragma unroll
        for (int mt = 0; mt < 2; ++mt)
            #pragma unroll
            for (int kk = 0; kk < 6; ++kk)
                aa[mt][kk] = *(const bf16x8*)&x_lds[(32 * mh + 16 * mt + c) * XS + kk * 32 + g * 8];

        float* og = out_g + (size_t)b * (NTOK * DIMC);
        #pragma unroll
        for (int nt = 0; nt < 3; ++nt) {
            const int cg = 48 * cq4 + nt * 16 + c;
            bf16x8 bw[6];
            #pragma unroll
            for (int kk = 0; kk < 6; ++kk) {
                if constexpr (MODE >= 1)
                    bw[kk] = pw[nt][kk];
                else
                    bw[kk] = cvt8(projw_g + (size_t)cg * DIMC + kk * 32 + g * 8);
            }
            const float bias = bp[cg];
            f32x4 acc[2];
            acc[0] = (f32x4){bias, bias, bias, bias};
            acc[1] = acc[0];
            #pragma unroll
            for (int kk = 0; kk < 6; ++kk)
                #pragma unroll
                for (int mt = 0; mt < 2; ++mt)
                    acc[mt] = __builtin_amdgcn_mfma_f32_16x16x32_bf16(aa[mt][kk], bw[kk], acc[mt], 0, 0, 0);
            #pragma unroll
            for (int mt = 0; mt < 2; ++mt)
                #pragma unroll
                for (int r = 0; r < 4; ++r) {
                    const int row = 32 * mh + 16 * mt + g * 4 + r;
                    if (row < NTOK) og[row * DIMC + cg] = acc[mt][r];
                }
        }
    }
}

extern "C" void kernel_launch(void* const* d_in, const int* in_sizes, int n_in,
                              void* d_out, int out_size, void* d_ws, size_t ws_size,
                              hipStream_t stream) {
    (void)in_sizes; (void)n_in; (void)out_size;
    const float* x_g     = (const float*)d_in[0];
    const float* mask_g  = (const float*)d_in[1];
    const float* rpb_g   = (const float*)d_in[2];
    const int*   rel_g   = (const int*)d_in[3];
    const float* qkvw_g  = (const float*)d_in[4];
    const float* qkvb_g  = (const float*)d_in[5];
    const float* projw_g = (const float*)d_in[6];
    const float* projb_g = (const float*)d_in[7];
    float*       out_g   = (float*)d_out;

    const bool has_w = (d_ws != nullptr) && (ws_size >= WS_NEED1);
    const bool has_b = (d_ws != nullptr) && (ws_size >= WS_NEED2);
    ushort_t* wbf = (ushort_t*)d_ws;
    float* bias4 = (float*)((char*)d_ws + WBF_BYTES);

    if (has_w) {
        int ngrp = QKV_GRP + PROJ_GRP;
        hipLaunchKernelGGL(swz_weights_kernel, dim3((ngrp + 255) / 256), dim3(256), 0, stream,
                           qkvw_g, projw_g, wbf);
    }
    if (has_b) {
        int nthr = BIAS_FLOATS / 4;
        hipLaunchKernelGGL(bias_kernel, dim3((nthr + 255) / 256), dim3(256), 0, stream,
                           mask_g, rpb_g, rel_g, bias4);
        hipFuncSetAttribute((const void*)win_attn_kernel<2>,
                            hipFuncAttributeMaxDynamicSharedMemorySize, SMEM_BYTES);
        hipLaunchKernelGGL(win_attn_kernel<2>, dim3(4096), dim3(512), SMEM_BYTES, stream,
                           x_g, mask_g, rpb_g, rel_g, qkvw_g, qkvb_g, projw_g, projb_g,
                           wbf, bias4, out_g);
    } else if (has_w) {
        hipFuncSetAttribute((const void*)win_attn_kernel<1>,
                            hipFuncAttributeMaxDynamicSharedMemorySize, SMEM_BYTES);
        hipLaunchKernelGGL(win_attn_kernel<1>, dim3(4096), dim3(512), SMEM_BYTES, stream,
                           x_g, mask_g, rpb_g, rel_g, qkvw_g, qkvb_g, projw_g, projb_g,
                           wbf, (const float*)nullptr, out_g);
    } else {
        hipFuncSetAttribute((const void*)win_attn_kernel<0>,
                            hipFuncAttributeMaxDynamicSharedMemorySize, SMEM_BYTES);
        hipLaunchKernelGGL(win_attn_kernel<0>, dim3(4096), dim3(512), SMEM_BYTES, stream,
                           x_g, mask_g, rpb_g, rel_g, qkvw_g, qkvb_g, projw_g, projb_g,
                           (const ushort_t*)nullptr, (const float*)nullptr, out_g);
    }
}

// Round 17
// 206.481 us; speedup vs baseline: 1.2413x; 1.2413x over previous
//
#include <hip/hip_runtime.h>
#include <stdint.h>
#include <cmath>

typedef unsigned short ushort_t;
typedef __attribute__((ext_vector_type(8))) short bf16x8;
typedef __attribute__((ext_vector_type(4))) float f32x4;
typedef __attribute__((ext_vector_type(4))) unsigned int u32x4;

#define NTOK 49
#define DIMC 192
#define NH 6
#define HD 32
#define SCALE 0.17677669529663687f
#define LOG2E 1.4426950408889634f
#define LN2   0.6931471805599453f
#define XS 200      // x/q/k/ao row stride (bf16 elems)
#define VTS 72      // vT row stride (tokens)
#define PS 72       // P row stride
#define MS 66       // mask row stride (f32)  [MODE<2 only]
#define RS 68       // rel row stride (u16)   [MODE<2 only]

// LDS carve (bytes), all 16B aligned
#define OFF_X    0          // [64][200] bf16 : x, later attn-out (ao)
#define OFF_Q    25600      // [64][200] bf16
#define OFF_K    51200      // [64][200] bf16
#define OFF_VT   76800      // [192][72] bf16
#define OFF_P    104448     // [8][16][72] bf16
#define OFF_MASK 122880     // [64][66] f32      [MODE<2]
#define OFF_RPB  139776     // [169][8] f32      [MODE<2]
#define OFF_REL  145184     // [64][68] u16      [MODE<2]
#define OFF_BQ   153888     // [576] f32
#define OFF_BP   156192     // [192] f32
#define SMEM_BYTES 156960

#define QKVW_N (576 * 192)
#define PROJW_N (192 * 192)
#define QKV_GRP (4 * 9 * 6 * 64)
#define PROJ_GRP (4 * 3 * 6 * 64)
#define WBF_BYTES ((QKVW_N + PROJW_N) * 2)
#define BIAS_FLOATS (64 * 6 * 4 * 4 * 4 * 16 * 4)
#define WS_NEED1 ((size_t)WBF_BYTES)
#define WS_NEED2 ((size_t)WBF_BYTES + (size_t)BIAS_FLOATS * 4)

__device__ __forceinline__ ushort_t f2bf(float f) {
    uint32_t x = __builtin_bit_cast(uint32_t, f);
    x += 0x7fffu + ((x >> 16) & 1u);   // RNE
    return (ushort_t)(x >> 16);
}
__device__ __forceinline__ uint32_t cvtpk(float lo, float hi) {   // packed RNE f32->bf16 pair
    uint32_t r;
    asm("v_cvt_pk_bf16_f32 %0, %1, %2" : "=v"(r) : "v"(lo), "v"(hi));
    return r;
}

__device__ __forceinline__ bf16x8 cvt8(const float* p) {
    f32x4 a = *(const f32x4*)p;
    f32x4 b = *(const f32x4*)(p + 4);
    bf16x8 r;
    r[0] = (short)f2bf(a[0]); r[1] = (short)f2bf(a[1]);
    r[2] = (short)f2bf(a[2]); r[3] = (short)f2bf(a[3]);
    r[4] = (short)f2bf(b[0]); r[5] = (short)f2bf(b[1]);
    r[6] = (short)f2bf(b[2]); r[7] = (short)f2bf(b[3]);
    return r;
}

// ---- pre-pass 1: f32 weights -> bf16, MFMA-fragment-swizzled ----
// q-cols pre-scaled by SCALE*LOG2E so QK^T score is already in exp2 domain.
__global__ __launch_bounds__(256) void swz_weights_kernel(
    const float* __restrict__ qkvw, const float* __restrict__ projw,
    ushort_t* __restrict__ dst)
{
    int i = blockIdx.x * 256 + threadIdx.x;
    if (i >= QKV_GRP + PROJ_GRP) return;
    const float* src;
    float s = 1.0f;
    if (i < QKV_GRP) {
        int lane = i & 63, t = i >> 6;
        int kk = t % 6, nt = (t / 6) % 9, cq = t / 54;
        int col = cq * 144 + nt * 16 + (lane & 15);
        int k0 = kk * 32 + (lane >> 4) * 8;
        src = qkvw + col * DIMC + k0;
        if (col < 192) s = SCALE * LOG2E;       // fold 1/sqrt(hd) * log2(e)
    } else {
        int j = i - QKV_GRP;
        int lane = j & 63, t = j >> 6;
        int kk = t % 6, nt = (t / 6) % 3, cq = t / 18;
        int col = cq * 48 + nt * 16 + (lane & 15);
        int k0 = kk * 32 + (lane >> 4) * 8;
        src = projw + col * DIMC + k0;
    }
    f32x4 a = *(const f32x4*)src;
    f32x4 b = *(const f32x4*)(src + 4);
    u32x4 o;
    o[0] = (uint32_t)f2bf(a[0] * s) | ((uint32_t)f2bf(a[1] * s) << 16);
    o[1] = (uint32_t)f2bf(a[2] * s) | ((uint32_t)f2bf(a[3] * s) << 16);
    o[2] = (uint32_t)f2bf(b[0] * s) | ((uint32_t)f2bf(b[1] * s) << 16);
    o[3] = (uint32_t)f2bf(b[2] * s) | ((uint32_t)f2bf(b[3] * s) << 16);
    *(u32x4*)(dst + (size_t)i * 8) = o;
}

// ---- pre-pass 2: bias in MFMA C-fragment order, scaled by LOG2E (exp2 domain) ----
__global__ __launch_bounds__(256) void bias_kernel(
    const float* __restrict__ mask_g, const float* __restrict__ rpb_g,
    const int* __restrict__ rel_g, float* __restrict__ dst)
{
    int i = blockIdx.x * 256 + threadIdx.x;
    if (i >= BIAS_FLOATS / 4) return;
    int c = i & 15, g = (i >> 4) & 3, t = (i >> 6) & 3, wsid = (i >> 8) & 3;
    int hw = i >> 10;
    int h = hw % 6, wi = hw / 6;
    int m0 = 16 * wsid + 4 * g, n = 16 * t + c;
    f32x4 v;
    #pragma unroll
    for (int r = 0; r < 4; ++r) {
        int m = m0 + r;
        float val;
        if (n >= NTOK)      val = -30000.0f;
        else if (m >= NTOK) val = 0.0f;
        else val = mask_g[(size_t)wi * (NTOK * NTOK) + m * NTOK + n]
                 + rpb_g[(size_t)rel_g[m * NTOK + n] * NH + h];
        v[r] = val * LOG2E;
    }
    *(f32x4*)(dst + (size_t)i * 4) = v;
}

// MODE: 2 = swizzled weights + precomputed bias, 1 = swizzled weights, 0 = raw
template <int MODE>
__global__ __launch_bounds__(512, 2) void win_attn_kernel(
    const float* __restrict__ x_g,
    const float* __restrict__ mask_g,
    const float* __restrict__ rpb_g,
    const int* __restrict__ rel_g,
    const float* __restrict__ qkvw_g,
    const float* __restrict__ qkvb_g,
    const float* __restrict__ projw_g,
    const float* __restrict__ projb_g,
    const ushort_t* __restrict__ wbf_g,
    const float* __restrict__ bias_g,
    float* __restrict__ out_g)
{
    extern __shared__ char smem[];
    ushort_t* x_lds  = (ushort_t*)(smem + OFF_X);
    ushort_t* q_lds  = (ushort_t*)(smem + OFF_Q);
    ushort_t* k_lds  = (ushort_t*)(smem + OFF_K);
    ushort_t* vT     = (ushort_t*)(smem + OFF_VT);
    ushort_t* P_lds  = (ushort_t*)(smem + OFF_P);
    float*    mask_p = (float*)(smem + OFF_MASK);
    float*    rpb_l  = (float*)(smem + OFF_RPB);
    ushort_t* rel_p  = (ushort_t*)(smem + OFF_REL);
    float*    bq     = (float*)(smem + OFF_BQ);
    float*    bp     = (float*)(smem + OFF_BP);

    const int tid  = threadIdx.x;
    const int b    = blockIdx.x;
    const int wi   = b & 63;
    const int w    = tid >> 6;
    const int lane = tid & 63;
    const int g    = lane >> 4;
    const int c    = lane & 15;

    // ---- QKV weight ring: ISSUE BEFORE STAGE (no LDS dep; hides under stage+barrier) ----
    bf16x8 ring[4][6];
    {
        if constexpr (MODE >= 1) {
            const int cq = w & 3;
            const ushort_t* wq = wbf_g + (size_t)cq * (9 * 6 * 64 * 8);
            #pragma unroll
            for (int p = 0; p < 3; ++p)
                #pragma unroll
                for (int kk = 0; kk < 6; ++kk)
                    ring[p][kk] = *(const bf16x8*)(wq + (size_t)((p * 6 + kk) * 64 + lane) * 8);
            __builtin_amdgcn_sched_barrier(0);   // pin: issued before anything below
        }
    }

    // ---------------- stage ----------------
    {
        const float* xg = x_g + (size_t)b * (NTOK * DIMC);
        for (int i = tid; i < 64 * 24; i += 512) {
            int row = i / 24, col = (i % 24) * 8;
            u32x4 v = {0u, 0u, 0u, 0u};
            if (row < NTOK) {
                const float* src = xg + row * DIMC + col;
                f32x4 a = *(const f32x4*)src;
                f32x4 d = *(const f32x4*)(src + 4);
                v[0] = cvtpk(a[0], a[1]); v[1] = cvtpk(a[2], a[3]);
                v[2] = cvtpk(d[0], d[1]); v[3] = cvtpk(d[2], d[3]);
            }
            *(u32x4*)&x_lds[row * XS + col] = v;
        }
        if constexpr (MODE < 2) {
            const float* mw = mask_g + (size_t)wi * (NTOK * NTOK);
            for (int i = tid; i < 64 * 64; i += 512) {
                int m = i >> 6, n = i & 63;
                float f;
                if (n >= NTOK)      f = -30000.0f;
                else if (m >= NTOK) f = 0.0f;
                else                f = mw[m * NTOK + n];
                mask_p[m * MS + n] = f;
                rel_p[m * RS + n] = (m < NTOK && n < NTOK) ? (ushort_t)rel_g[m * NTOK + n]
                                                           : (ushort_t)0;
            }
            for (int i = tid; i < 169 * 6; i += 512)
                rpb_l[(i / 6) * 8 + (i % 6)] = rpb_g[i];
        }
        for (int i = tid; i < 576; i += 512) {
            float v = qkvb_g[i];
            if constexpr (MODE >= 1) { if (i < 192) v *= SCALE * LOG2E; }
            bq[i] = v;
        }
        if (tid < 192) bp[tid] = projb_g[tid];
    }
    __syncthreads();

    // ---------------- QKV GEMM: wave (mh = w>>2, cq = w&3) ----------------
    {
        const int mh = w >> 2, cq = w & 3;
        const ushort_t* wq = wbf_g + (size_t)cq * (9 * 6 * 64 * 8);

        bf16x8 ax[2][6];
        #pragma unroll
        for (int mt = 0; mt < 2; ++mt)
            #pragma unroll
            for (int kk = 0; kk < 6; ++kk)
                ax[mt][kk] = *(const bf16x8*)&x_lds[(32 * mh + 16 * mt + c) * XS + kk * 32 + g * 8];

        #pragma unroll
        for (int nt = 0; nt < 9; ++nt) {
            const int cg = 144 * cq + nt * 16 + c;
            bf16x8 bw[6];
            if constexpr (MODE >= 1) {
                if (nt + 3 < 9) {
                    #pragma unroll
                    for (int kk = 0; kk < 6; ++kk)
                        ring[(nt + 3) & 3][kk] =
                            *(const bf16x8*)(wq + (size_t)(((nt + 3) * 6 + kk) * 64 + lane) * 8);
                }
                __builtin_amdgcn_sched_barrier(0);
                #pragma unroll
                for (int kk = 0; kk < 6; ++kk) bw[kk] = ring[nt & 3][kk];
            } else {
                #pragma unroll
                for (int kk = 0; kk < 6; ++kk)
                    bw[kk] = cvt8(qkvw_g + (size_t)cg * DIMC + kk * 32 + g * 8);
            }
            const float bias = bq[cg];
            f32x4 acc[2];
            acc[0] = (f32x4){bias, bias, bias, bias};
            acc[1] = acc[0];
            #pragma unroll
            for (int kk = 0; kk < 6; ++kk)
                #pragma unroll
                for (int mt = 0; mt < 2; ++mt)
                    acc[mt] = __builtin_amdgcn_mfma_f32_16x16x32_bf16(ax[mt][kk], bw[kk], acc[mt], 0, 0, 0);

            const int seg = 144 * cq + nt * 16;
            if (seg < 192) {            // q (exp2-domain pre-scaled in MODE>=1)
                #pragma unroll
                for (int mt = 0; mt < 2; ++mt) {
                    uint32_t p01 = cvtpk(acc[mt][0], acc[mt][1]);
                    uint32_t p23 = cvtpk(acc[mt][2], acc[mt][3]);
                    const int r0 = 32 * mh + 16 * mt + g * 4;
                    q_lds[(r0 + 0) * XS + cg] = (ushort_t)p01;
                    q_lds[(r0 + 1) * XS + cg] = (ushort_t)(p01 >> 16);
                    q_lds[(r0 + 2) * XS + cg] = (ushort_t)p23;
                    q_lds[(r0 + 3) * XS + cg] = (ushort_t)(p23 >> 16);
                }
            } else if (seg < 384) {     // k
                const int ck = cg - 192;
                #pragma unroll
                for (int mt = 0; mt < 2; ++mt) {
                    uint32_t p01 = cvtpk(acc[mt][0], acc[mt][1]);
                    uint32_t p23 = cvtpk(acc[mt][2], acc[mt][3]);
                    const int r0 = 32 * mh + 16 * mt + g * 4;
                    k_lds[(r0 + 0) * XS + ck] = (ushort_t)p01;
                    k_lds[(r0 + 1) * XS + ck] = (ushort_t)(p01 >> 16);
                    k_lds[(r0 + 2) * XS + ck] = (ushort_t)p23;
                    k_lds[(r0 + 3) * XS + ck] = (ushort_t)(p23 >> 16);
                }
            } else {                    // v -> vT[h*32+dim][token]
                const int cv = cg - 384;
                #pragma unroll
                for (int mt = 0; mt < 2; ++mt) {
                    uint32_t* dst = (uint32_t*)&vT[cv * VTS + 32 * mh + 16 * mt + g * 4];
                    dst[0] = cvtpk(acc[mt][0], acc[mt][1]);
                    dst[1] = cvtpk(acc[mt][2], acc[mt][3]);
                }
            }
        }
    }
    __syncthreads();

    // ---------------- attention: wave (wsid = w&3, hh = w>>2) ----------------
    bf16x8 pw[3][6];
    {
        const int wsid = w & 3, hh = w >> 2;
        ushort_t* Pw = P_lds + w * (16 * PS);
        const int mq0 = 16 * wsid + g * 4;

        if constexpr (MODE == 2) {
            // pipelined: QKT0,QKT1,SM0,QKT2,PV0,SM1,PV1,[pw],SM2,PV2
            const int h0 = hh * 3;
            f32x4 S0[4], S1[4], S2[4];
            const short oneb = (short)0x3F80;            // bf16 1.0
            bf16x8 ones8 = {oneb, oneb, oneb, oneb, oneb, oneb, oneb, oneb};

            auto QKT = [&](int h, f32x4* S) {
                bf16x8 aq = *(const bf16x8*)&q_lds[(16 * wsid + c) * XS + h * HD + g * 8];
                const float* bC = bias_g + ((size_t)((wi * 6 + h) * 4 + wsid) * 4) * 256 + lane * 4;
                __builtin_amdgcn_s_setprio(1);
                #pragma unroll
                for (int t = 0; t < 4; ++t) {
                    f32x4 Ct = *(const f32x4*)(bC + t * 256);
                    bf16x8 bk = *(const bf16x8*)&k_lds[(16 * t + c) * XS + h * HD + g * 8];
                    S[t] = __builtin_amdgcn_mfma_f32_16x16x32_bf16(aq, bk, Ct, 0, 0, 0);
                }
                __builtin_amdgcn_s_setprio(0);
            };
            // P = exp2(S) (score already in exp2 domain); no max, no sum here
            auto SM = [&](f32x4* S) {
                #pragma unroll
                for (int r = 0; r < 4; ++r) {
                    float e0 = exp2f(S[0][r]), e1 = exp2f(S[1][r]);
                    float e2 = exp2f(S[2][r]), e3 = exp2f(S[3][r]);
                    uint32_t p01 = cvtpk(e0, e1);
                    uint32_t p23 = cvtpk(e2, e3);
                    ushort_t* pr = Pw + (g * 4 + r) * PS + c;
                    pr[0]  = (ushort_t)p01;
                    pr[16] = (ushort_t)(p01 >> 16);
                    pr[32] = (ushort_t)p23;
                    pr[48] = (ushort_t)(p23 >> 16);
                }
            };
            // PV + MFMA row-sum (ones B tile): D[r][c] = rowsum for all c -> rinv in-lane
            auto PV = [&](int h) {
                f32x4 z = {0.f, 0.f, 0.f, 0.f};
                f32x4 O[2] = {z, z};
                f32x4 Osum = z;
                __builtin_amdgcn_s_setprio(1);
                #pragma unroll
                for (int ks = 0; ks < 2; ++ks) {
                    bf16x8 ap = *(const bf16x8*)&Pw[c * PS + ks * 32 + g * 8];
                    #pragma unroll
                    for (int nt = 0; nt < 2; ++nt) {
                        bf16x8 bv = *(const bf16x8*)&vT[(h * HD + nt * 16 + c) * VTS + ks * 32 + g * 8];
                        O[nt] = __builtin_amdgcn_mfma_f32_16x16x32_bf16(ap, bv, O[nt], 0, 0, 0);
                    }
                    Osum = __builtin_amdgcn_mfma_f32_16x16x32_bf16(ap, ones8, Osum, 0, 0, 0);
                }
                __builtin_amdgcn_s_setprio(0);
                #pragma unroll
                for (int r = 0; r < 4; ++r) {
                    float rinv = 1.0f / Osum[r];
                    uint32_t po = cvtpk(O[0][r] * rinv, O[1][r] * rinv);
                    ushort_t* ar = x_lds + (16 * wsid + g * 4 + r) * XS + h * HD + c;
                    ar[0]  = (ushort_t)po;
                    ar[16] = (ushort_t)(po >> 16);
                }
            };

            QKT(h0 + 0, S0);
            QKT(h0 + 1, S1);
            SM(S0);
            QKT(h0 + 2, S2);
            PV(h0 + 0);
            SM(S1);                 // P1 write after PV0 read (program order, same wave)
            PV(h0 + 1);
            {                       // proj weights; short liveness
                const int cq4 = w & 3;
                const ushort_t* wp = wbf_g + QKVW_N + (size_t)cq4 * (3 * 6 * 64 * 8);
                #pragma unroll
                for (int nt = 0; nt < 3; ++nt)
                    #pragma unroll
                    for (int kk = 0; kk < 6; ++kk)
                        pw[nt][kk] = *(const bf16x8*)(wp + (size_t)((nt * 6 + kk) * 64 + lane) * 8);
                __builtin_amdgcn_sched_barrier(0);
            }
            SM(S2);
            PV(h0 + 2);
        } else {
            auto head = [&](int h) {
                bf16x8 aq = *(const bf16x8*)&q_lds[(16 * wsid + c) * XS + h * HD + g * 8];
                f32x4 S[4];
                #pragma unroll
                for (int t = 0; t < 4; ++t) {
                    bf16x8 bk = *(const bf16x8*)&k_lds[(16 * t + c) * XS + h * HD + g * 8];
                    f32x4 z = {0.f, 0.f, 0.f, 0.f};
                    S[t] = __builtin_amdgcn_mfma_f32_16x16x32_bf16(aq, bk, z, 0, 0, 0);
                }
                float rinv[4];
                #pragma unroll
                for (int r = 0; r < 4; ++r) {
                    const int mq = mq0 + r;
                    const float*    mrow = mask_p + mq * MS;
                    const ushort_t* rrow = rel_p + mq * RS;
                    float sv[4];
                    #pragma unroll
                    for (int t = 0; t < 4; ++t) {
                        const int n = 16 * t + c;
                        // MODE1: swz q includes SCALE*LOG2E -> undo LOG2E; MODE0: raw
                        float sc = (MODE == 0) ? SCALE : LN2;
                        sv[t] = S[t][r] * sc + rpb_l[(int)rrow[n] * 8 + h] + mrow[n];
                    }
                    float vmax = fmaxf(fmaxf(sv[0], sv[1]), fmaxf(sv[2], sv[3]));
                    #pragma unroll
                    for (int xm = 1; xm < 16; xm <<= 1)
                        vmax = fmaxf(vmax, __shfl_xor(vmax, xm));
                    float sum = 0.f;
                    float ev[4];
                    #pragma unroll
                    for (int t = 0; t < 4; ++t) {
                        ev[t] = __expf(fmaxf(sv[t] - vmax, -80.0f));
                        sum += ev[t];
                    }
                    #pragma unroll
                    for (int xm = 1; xm < 16; xm <<= 1)
                        sum += __shfl_xor(sum, xm);
                    rinv[r] = 1.0f / sum;
                    uint32_t p01 = cvtpk(ev[0], ev[1]);
                    uint32_t p23 = cvtpk(ev[2], ev[3]);
                    ushort_t* pr = Pw + (g * 4 + r) * PS + c;
                    pr[0]  = (ushort_t)p01;
                    pr[16] = (ushort_t)(p01 >> 16);
                    pr[32] = (ushort_t)p23;
                    pr[48] = (ushort_t)(p23 >> 16);
                }
                f32x4 z = {0.f, 0.f, 0.f, 0.f};
                f32x4 O[2] = {z, z};
                #pragma unroll
                for (int ks = 0; ks < 2; ++ks) {
                    bf16x8 ap = *(const bf16x8*)&Pw[c * PS + ks * 32 + g * 8];
                    #pragma unroll
                    for (int nt = 0; nt < 2; ++nt) {
                        bf16x8 bv = *(const bf16x8*)&vT[(h * HD + nt * 16 + c) * VTS + ks * 32 + g * 8];
                        O[nt] = __builtin_amdgcn_mfma_f32_16x16x32_bf16(ap, bv, O[nt], 0, 0, 0);
                    }
                }
                #pragma unroll
                for (int r = 0; r < 4; ++r) {
                    uint32_t po = cvtpk(O[0][r] * rinv[r], O[1][r] * rinv[r]);
                    ushort_t* ar = x_lds + (16 * wsid + g * 4 + r) * XS + h * HD + c;
                    ar[0]  = (ushort_t)po;
                    ar[16] = (ushort_t)(po >> 16);
                }
            };
            head(hh * 3 + 0);
            head(hh * 3 + 1);
            if constexpr (MODE >= 1) {
                const int cq4 = w & 3;
                const ushort_t* wp = wbf_g + QKVW_N + (size_t)cq4 * (3 * 6 * 64 * 8);
                #pragma unroll
                for (int nt = 0; nt < 3; ++nt)
                    #pragma unroll
                    for (int kk = 0; kk < 6; ++kk)
                        pw[nt][kk] = *(const bf16x8*)(wp + (size_t)((nt * 6 + kk) * 64 + lane) * 8);
                __builtin_amdgcn_sched_barrier(0);
            }
            head(hh * 3 + 2);
        }
    }
    __syncthreads();

    // ---------------- proj GEMM -> direct f32 global store ----------------
    {
        const int mh = w >> 2, cq4 = w & 3;
        bf16x8 aa[2][6];
        #pragma unroll
        for (int mt = 0; mt < 2; ++mt)
            #pragma unroll
            for (int kk = 0; kk < 6; ++kk)
                aa[mt][kk] = *(const bf16x8*)&x_lds[(32 * mh + 16 * mt + c) * XS + kk * 32 + g * 8];

        float* og = out_g + (size_t)b * (NTOK * DIMC);
        #pragma unroll
        for (int nt = 0; nt < 3; ++nt) {
            const int cg = 48 * cq4 + nt * 16 + c;
            bf16x8 bw[6];
            #pragma unroll
            for (int kk = 0; kk < 6; ++kk) {
                if constexpr (MODE >= 1)
                    bw[kk] = pw[nt][kk];
                else
                    bw[kk] = cvt8(projw_g + (size_t)cg * DIMC + kk * 32 + g * 8);
            }
            const float bias = bp[cg];
            f32x4 acc[2];
            acc[0] = (f32x4){bias, bias, bias, bias};
            acc[1] = acc[0];
            #pragma unroll
            for (int kk = 0; kk < 6; ++kk)
                #pragma unroll
                for (int mt = 0; mt < 2; ++mt)
                    acc[mt] = __builtin_amdgcn_mfma_f32_16x16x32_bf16(aa[mt][kk], bw[kk], acc[mt], 0, 0, 0);
            #pragma unroll
            for (int mt = 0; mt < 2; ++mt)
                #pragma unroll
                for (int r = 0; r < 4; ++r) {
                    const int row = 32 * mh + 16 * mt + g * 4 + r;
                    if (row < NTOK) og[row * DIMC + cg] = acc[mt][r];
                }
        }
    }
}

extern "C" void kernel_launch(void* const* d_in, const int* in_sizes, int n_in,
                              void* d_out, int out_size, void* d_ws, size_t ws_size,
                              hipStream_t stream) {
    (void)in_sizes; (void)n_in; (void)out_size;
    const float* x_g     = (const float*)d_in[0];
    const float* mask_g  = (const float*)d_in[1];
    const float* rpb_g   = (const float*)d_in[2];
    const int*   rel_g   = (const int*)d_in[3];
    const float* qkvw_g  = (const float*)d_in[4];
    const float* qkvb_g  = (const float*)d_in[5];
    const float* projw_g = (const float*)d_in[6];
    const float* projb_g = (const float*)d_in[7];
    float*       out_g   = (float*)d_out;

    const bool has_w = (d_ws != nullptr) && (ws_size >= WS_NEED1);
    const bool has_b = (d_ws != nullptr) && (ws_size >= WS_NEED2);
    ushort_t* wbf = (ushort_t*)d_ws;
    float* bias4 = (float*)((char*)d_ws + WBF_BYTES);

    if (has_w) {
        int ngrp = QKV_GRP + PROJ_GRP;
        hipLaunchKernelGGL(swz_weights_kernel, dim3((ngrp + 255) / 256), dim3(256), 0, stream,
                           qkvw_g, projw_g, wbf);
    }
    if (has_b) {
        int nthr = BIAS_FLOATS / 4;
        hipLaunchKernelGGL(bias_kernel, dim3((nthr + 255) / 256), dim3(256), 0, stream,
                           mask_g, rpb_g, rel_g, bias4);
        hipFuncSetAttribute((const void*)win_attn_kernel<2>,
                            hipFuncAttributeMaxDynamicSharedMemorySize, SMEM_BYTES);
        hipLaunchKernelGGL(win_attn_kernel<2>, dim3(4096), dim3(512), SMEM_BYTES, stream,
                           x_g, mask_g, rpb_g, rel_g, qkvw_g, qkvb_g, projw_g, projb_g,
                           wbf, bias4, out_g);
    } else if (has_w) {
        hipFuncSetAttribute((const void*)win_attn_kernel<1>,
                            hipFuncAttributeMaxDynamicSharedMemorySize, SMEM_BYTES);
        hipLaunchKernelGGL(win_attn_kernel<1>, dim3(4096), dim3(512), SMEM_BYTES, stream,
                           x_g, mask_g, rpb_g, rel_g, qkvw_g, qkvb_g, projw_g, projb_g,
                           wbf, (const float*)nullptr, out_g);
    } else {
        hipFuncSetAttribute((const void*)win_attn_kernel<0>,
                            hipFuncAttributeMaxDynamicSharedMemorySize, SMEM_BYTES);
        hipLaunchKernelGGL(win_attn_kernel<0>, dim3(4096), dim3(512), SMEM_BYTES, stream,
                           x_g, mask_g, rpb_g, rel_g, qkvw_g, qkvb_g, projw_g, projb_g,
                           (const ushort_t*)nullptr, (const float*)nullptr, out_g);
    }
}

// Round 18
// 202.233 us; speedup vs baseline: 1.2674x; 1.0210x over previous
//
#include <hip/hip_runtime.h>
#include <stdint.h>
#include <cmath>

typedef unsigned short ushort_t;
typedef __attribute__((ext_vector_type(8))) short bf16x8;
typedef __attribute__((ext_vector_type(4))) float f32x4;
typedef __attribute__((ext_vector_type(4))) unsigned int u32x4;

#define NTOK 49
#define DIMC 192
#define NH 6
#define HD 32
#define SCALE 0.17677669529663687f
#define LOG2E 1.4426950408889634f
#define XS 200      // x/q/k/ao row stride (bf16 elems)
#define VTS 72      // vT row stride (tokens)
#define PS 72       // P row stride
#define MS 66       // mask row stride (f32)  [fallback only]
#define RS 68       // rel row stride (u16)   [fallback only]

// ---- 12-wave MODE2 LDS carve (bytes) ----
#define OFF_X    0          // [64][200] bf16 : x, later attn-out (ao)
#define OFF_Q    25600      // [64][200] bf16
#define OFF_K    51200      // [64][200] bf16
#define OFF_VT   76800      // [192][72] bf16
#define OFF_P    104448     // [12][16][72] bf16
#define OFF_BQ   132096     // [576] f32
#define OFF_BP   134400     // [192] f32
#define SMEM12   135168

// ---- fallback (512-thread) LDS carve ----
#define FOFF_X    0
#define FOFF_Q    25600
#define FOFF_K    51200
#define FOFF_VT   76800
#define FOFF_P    104448    // [8][16][72]
#define FOFF_MASK 122880
#define FOFF_RPB  139776
#define FOFF_REL  145184
#define FOFF_BQ   153888
#define FOFF_BP   156192
#define FSMEM     156960

#define QKVW_N (576 * 192)
#define PROJW_N (192 * 192)
#define QKV_GRP (4 * 9 * 6 * 64)
#define PROJ_GRP (4 * 3 * 6 * 64)
#define WBF_BYTES ((QKVW_N + PROJW_N) * 2)
#define BIAS_FLOATS (64 * 6 * 4 * 4 * 4 * 16 * 4)
#define WS_NEED1 ((size_t)WBF_BYTES)
#define WS_NEED2 ((size_t)WBF_BYTES + (size_t)BIAS_FLOATS * 4)

__device__ __forceinline__ ushort_t f2bf(float f) {
    uint32_t x = __builtin_bit_cast(uint32_t, f);
    x += 0x7fffu + ((x >> 16) & 1u);   // RNE
    return (ushort_t)(x >> 16);
}
__device__ __forceinline__ uint32_t cvtpk(float lo, float hi) {   // packed RNE f32->bf16 pair
    uint32_t r;
    asm("v_cvt_pk_bf16_f32 %0, %1, %2" : "=v"(r) : "v"(lo), "v"(hi));
    return r;
}
__device__ __forceinline__ bf16x8 cvt8(const float* p) {
    f32x4 a = *(const f32x4*)p;
    f32x4 b = *(const f32x4*)(p + 4);
    bf16x8 r;
    r[0] = (short)f2bf(a[0]); r[1] = (short)f2bf(a[1]);
    r[2] = (short)f2bf(a[2]); r[3] = (short)f2bf(a[3]);
    r[4] = (short)f2bf(b[0]); r[5] = (short)f2bf(b[1]);
    r[6] = (short)f2bf(b[2]); r[7] = (short)f2bf(b[3]);
    return r;
}

// ---- pre-pass 1: f32 weights -> bf16, MFMA-fragment-swizzled ----
__global__ __launch_bounds__(256) void swz_weights_kernel(
    const float* __restrict__ qkvw, const float* __restrict__ projw,
    ushort_t* __restrict__ dst)
{
    int i = blockIdx.x * 256 + threadIdx.x;
    if (i >= QKV_GRP + PROJ_GRP) return;
    const float* src;
    float s = 1.0f;
    if (i < QKV_GRP) {
        int lane = i & 63, t = i >> 6;
        int kk = t % 6, nt = (t / 6) % 9, cq = t / 54;
        int col = cq * 144 + nt * 16 + (lane & 15);
        int k0 = kk * 32 + (lane >> 4) * 8;
        src = qkvw + col * DIMC + k0;
        if (col < 192) s = SCALE * LOG2E;
    } else {
        int j = i - QKV_GRP;
        int lane = j & 63, t = j >> 6;
        int kk = t % 6, nt = (t / 6) % 3, cq = t / 18;
        int col = cq * 48 + nt * 16 + (lane & 15);
        int k0 = kk * 32 + (lane >> 4) * 8;
        src = projw + col * DIMC + k0;
    }
    f32x4 a = *(const f32x4*)src;
    f32x4 b = *(const f32x4*)(src + 4);
    u32x4 o;
    o[0] = (uint32_t)f2bf(a[0] * s) | ((uint32_t)f2bf(a[1] * s) << 16);
    o[1] = (uint32_t)f2bf(a[2] * s) | ((uint32_t)f2bf(a[3] * s) << 16);
    o[2] = (uint32_t)f2bf(b[0] * s) | ((uint32_t)f2bf(b[1] * s) << 16);
    o[3] = (uint32_t)f2bf(b[2] * s) | ((uint32_t)f2bf(b[3] * s) << 16);
    *(u32x4*)(dst + (size_t)i * 8) = o;
}

// ---- pre-pass 2: bias in MFMA C-fragment order, scaled by LOG2E ----
__global__ __launch_bounds__(256) void bias_kernel(
    const float* __restrict__ mask_g, const float* __restrict__ rpb_g,
    const int* __restrict__ rel_g, float* __restrict__ dst)
{
    int i = blockIdx.x * 256 + threadIdx.x;
    if (i >= BIAS_FLOATS / 4) return;
    int c = i & 15, g = (i >> 4) & 3, t = (i >> 6) & 3, wsid = (i >> 8) & 3;
    int hw = i >> 10;
    int h = hw % 6, wi = hw / 6;
    int m0 = 16 * wsid + 4 * g, n = 16 * t + c;
    f32x4 v;
    #pragma unroll
    for (int r = 0; r < 4; ++r) {
        int m = m0 + r;
        float val;
        if (n >= NTOK)      val = -30000.0f;
        else if (m >= NTOK) val = 0.0f;
        else val = mask_g[(size_t)wi * (NTOK * NTOK) + m * NTOK + n]
                 + rpb_g[(size_t)rel_g[m * NTOK + n] * NH + h];
        v[r] = val * LOG2E;
    }
    *(f32x4*)(dst + (size_t)i * 4) = v;
}

// ================= 12-wave fast path (MODE2) =================
__global__ __launch_bounds__(768, 1) void win_attn12_kernel(
    const float* __restrict__ x_g,
    const float* __restrict__ qkvb_g,
    const float* __restrict__ projb_g,
    const ushort_t* __restrict__ wbf_g,
    const float* __restrict__ bias_g,
    float* __restrict__ out_g)
{
    extern __shared__ char smem[];
    ushort_t* x_lds  = (ushort_t*)(smem + OFF_X);
    ushort_t* q_lds  = (ushort_t*)(smem + OFF_Q);
    ushort_t* k_lds  = (ushort_t*)(smem + OFF_K);
    ushort_t* vT     = (ushort_t*)(smem + OFF_VT);
    ushort_t* P_lds  = (ushort_t*)(smem + OFF_P);
    float*    bq     = (float*)(smem + OFF_BQ);
    float*    bp     = (float*)(smem + OFF_BP);

    const int tid  = threadIdx.x;
    const int b    = blockIdx.x;
    const int wi   = b & 63;
    const int w    = tid >> 6;         // wave 0..11
    const int lane = tid & 63;
    const int g    = lane >> 4;
    const int c    = lane & 15;

    // QKV split: rows [32mh,+32), col-tiles [6cgrp, 6cgrp+6) of 36
    const int mh = w / 6, cgrp = w % 6;
    const int ct0 = 6 * cgrp;

    // ---- weight ring: issue before stage (hides under stage+barrier) ----
    bf16x8 ring[4][6];
    #pragma unroll
    for (int p = 0; p < 3; ++p)
        #pragma unroll
        for (int kk = 0; kk < 6; ++kk)
            ring[p][kk] = *(const bf16x8*)(wbf_g + (size_t)(((ct0 + p) * 6 + kk) * 64 + lane) * 8);
    __builtin_amdgcn_sched_barrier(0);

    // ---------------- stage ----------------
    {
        const float* xg = x_g + (size_t)b * (NTOK * DIMC);
        for (int i = tid; i < 64 * 24; i += 768) {
            int row = i / 24, col = (i % 24) * 8;
            u32x4 v = {0u, 0u, 0u, 0u};
            if (row < NTOK) {
                const float* src = xg + row * DIMC + col;
                f32x4 a = *(const f32x4*)src;
                f32x4 d = *(const f32x4*)(src + 4);
                v[0] = cvtpk(a[0], a[1]); v[1] = cvtpk(a[2], a[3]);
                v[2] = cvtpk(d[0], d[1]); v[3] = cvtpk(d[2], d[3]);
            }
            *(u32x4*)&x_lds[row * XS + col] = v;
        }
        if (tid < 576) {
            float v = qkvb_g[tid];
            if (tid < 192) v *= SCALE * LOG2E;
            bq[tid] = v;
        }
        if (tid < 192) bp[tid] = projb_g[tid];
    }
    __syncthreads();

    // ---------------- QKV GEMM ----------------
    {
        bf16x8 ax[2][6];
        #pragma unroll
        for (int mt = 0; mt < 2; ++mt)
            #pragma unroll
            for (int kk = 0; kk < 6; ++kk)
                ax[mt][kk] = *(const bf16x8*)&x_lds[(32 * mh + 16 * mt + c) * XS + kk * 32 + g * 8];

        #pragma unroll
        for (int i = 0; i < 6; ++i) {
            const int ct = ct0 + i;
            const int cg = ct * 16 + c;
            if (i + 3 < 6) {
                #pragma unroll
                for (int kk = 0; kk < 6; ++kk)
                    ring[(i + 3) & 3][kk] =
                        *(const bf16x8*)(wbf_g + (size_t)(((ct0 + i + 3) * 6 + kk) * 64 + lane) * 8);
            }
            __builtin_amdgcn_sched_barrier(0);
            bf16x8 bw[6];
            #pragma unroll
            for (int kk = 0; kk < 6; ++kk) bw[kk] = ring[i & 3][kk];

            const float bias = bq[cg];
            f32x4 acc[2];
            acc[0] = (f32x4){bias, bias, bias, bias};
            acc[1] = acc[0];
            #pragma unroll
            for (int kk = 0; kk < 6; ++kk)
                #pragma unroll
                for (int mt = 0; mt < 2; ++mt)
                    acc[mt] = __builtin_amdgcn_mfma_f32_16x16x32_bf16(ax[mt][kk], bw[kk], acc[mt], 0, 0, 0);

            // wave-uniform segment: cgrp 0,1 -> q; 2,3 -> k; 4,5 -> v
            if (cgrp < 2) {
                #pragma unroll
                for (int mt = 0; mt < 2; ++mt) {
                    uint32_t p01 = cvtpk(acc[mt][0], acc[mt][1]);
                    uint32_t p23 = cvtpk(acc[mt][2], acc[mt][3]);
                    const int r0 = 32 * mh + 16 * mt + g * 4;
                    q_lds[(r0 + 0) * XS + cg] = (ushort_t)p01;
                    q_lds[(r0 + 1) * XS + cg] = (ushort_t)(p01 >> 16);
                    q_lds[(r0 + 2) * XS + cg] = (ushort_t)p23;
                    q_lds[(r0 + 3) * XS + cg] = (ushort_t)(p23 >> 16);
                }
            } else if (cgrp < 4) {
                const int ck = cg - 192;
                #pragma unroll
                for (int mt = 0; mt < 2; ++mt) {
                    uint32_t p01 = cvtpk(acc[mt][0], acc[mt][1]);
                    uint32_t p23 = cvtpk(acc[mt][2], acc[mt][3]);
                    const int r0 = 32 * mh + 16 * mt + g * 4;
                    k_lds[(r0 + 0) * XS + ck] = (ushort_t)p01;
                    k_lds[(r0 + 1) * XS + ck] = (ushort_t)(p01 >> 16);
                    k_lds[(r0 + 2) * XS + ck] = (ushort_t)p23;
                    k_lds[(r0 + 3) * XS + ck] = (ushort_t)(p23 >> 16);
                }
            } else {
                const int cv = cg - 384;
                #pragma unroll
                for (int mt = 0; mt < 2; ++mt) {
                    uint32_t* dst = (uint32_t*)&vT[cv * VTS + 32 * mh + 16 * mt + g * 4];
                    dst[0] = cvtpk(acc[mt][0], acc[mt][1]);
                    dst[1] = cvtpk(acc[mt][2], acc[mt][3]);
                }
            }
        }
    }
    __syncthreads();

    // ---------------- attention: wave (wsid = w&3, hp = w>>2): heads 2hp, 2hp+1 ----
    bf16x8 pw[6];
    {
        const int wsid = w & 3, hp = w >> 2;
        ushort_t* Pw = P_lds + w * (16 * PS);
        f32x4 S0[4], S1[4];
        const short oneb = (short)0x3F80;
        bf16x8 ones8 = {oneb, oneb, oneb, oneb, oneb, oneb, oneb, oneb};

        auto QKT = [&](int h, f32x4* S) {
            bf16x8 aq = *(const bf16x8*)&q_lds[(16 * wsid + c) * XS + h * HD + g * 8];
            const float* bC = bias_g + ((size_t)((wi * 6 + h) * 4 + wsid) * 4) * 256 + lane * 4;
            __builtin_amdgcn_s_setprio(1);
            #pragma unroll
            for (int t = 0; t < 4; ++t) {
                f32x4 Ct = *(const f32x4*)(bC + t * 256);
                bf16x8 bk = *(const bf16x8*)&k_lds[(16 * t + c) * XS + h * HD + g * 8];
                S[t] = __builtin_amdgcn_mfma_f32_16x16x32_bf16(aq, bk, Ct, 0, 0, 0);
            }
            __builtin_amdgcn_s_setprio(0);
        };
        auto SM = [&](f32x4* S) {
            #pragma unroll
            for (int r = 0; r < 4; ++r) {
                float e0 = exp2f(S[0][r]), e1 = exp2f(S[1][r]);
                float e2 = exp2f(S[2][r]), e3 = exp2f(S[3][r]);
                uint32_t p01 = cvtpk(e0, e1);
                uint32_t p23 = cvtpk(e2, e3);
                ushort_t* pr = Pw + (g * 4 + r) * PS + c;
                pr[0]  = (ushort_t)p01;
                pr[16] = (ushort_t)(p01 >> 16);
                pr[32] = (ushort_t)p23;
                pr[48] = (ushort_t)(p23 >> 16);
            }
        };
        auto PV = [&](int h) {
            f32x4 z = {0.f, 0.f, 0.f, 0.f};
            f32x4 O[2] = {z, z};
            f32x4 Osum = z;
            __builtin_amdgcn_s_setprio(1);
            #pragma unroll
            for (int ks = 0; ks < 2; ++ks) {
                bf16x8 ap = *(const bf16x8*)&Pw[c * PS + ks * 32 + g * 8];
                #pragma unroll
                for (int nt = 0; nt < 2; ++nt) {
                    bf16x8 bv = *(const bf16x8*)&vT[(h * HD + nt * 16 + c) * VTS + ks * 32 + g * 8];
                    O[nt] = __builtin_amdgcn_mfma_f32_16x16x32_bf16(ap, bv, O[nt], 0, 0, 0);
                }
                Osum = __builtin_amdgcn_mfma_f32_16x16x32_bf16(ap, ones8, Osum, 0, 0, 0);
            }
            __builtin_amdgcn_s_setprio(0);
            #pragma unroll
            for (int r = 0; r < 4; ++r) {
                float rinv = 1.0f / Osum[r];
                uint32_t po = cvtpk(O[0][r] * rinv, O[1][r] * rinv);
                ushort_t* ar = x_lds + (16 * wsid + g * 4 + r) * XS + h * HD + c;
                ar[0]  = (ushort_t)po;
                ar[16] = (ushort_t)(po >> 16);
            }
        };

        QKT(2 * hp + 0, S0);
        QKT(2 * hp + 1, S1);
        SM(S0);
        PV(2 * hp + 0);
        {   // proj weights for this wave's single col-tile; short liveness
            const ushort_t* wp = wbf_g + QKVW_N;
            #pragma unroll
            for (int kk = 0; kk < 6; ++kk)
                pw[kk] = *(const bf16x8*)(wp + (size_t)((w * 6 + kk) * 64 + lane) * 8);
            __builtin_amdgcn_sched_barrier(0);
        }
        SM(S1);                // P write after PV0 read (program order, same wave)
        PV(2 * hp + 1);
    }
    __syncthreads();

    // ---------------- proj GEMM: wave owns col-tile w (16 cols), rows in mt-pairs ----
    {
        const int cg = w * 16 + c;
        const float bias = bp[cg];
        float* og = out_g + (size_t)b * (NTOK * DIMC);
        #pragma unroll
        for (int mp = 0; mp < 2; ++mp) {
            bf16x8 aa[2][6];
            #pragma unroll
            for (int mt = 0; mt < 2; ++mt)
                #pragma unroll
                for (int kk = 0; kk < 6; ++kk)
                    aa[mt][kk] = *(const bf16x8*)&x_lds[(32 * mp + 16 * mt + c) * XS + kk * 32 + g * 8];
            f32x4 acc[2];
            acc[0] = (f32x4){bias, bias, bias, bias};
            acc[1] = acc[0];
            #pragma unroll
            for (int kk = 0; kk < 6; ++kk)
                #pragma unroll
                for (int mt = 0; mt < 2; ++mt)
                    acc[mt] = __builtin_amdgcn_mfma_f32_16x16x32_bf16(aa[mt][kk], pw[kk], acc[mt], 0, 0, 0);
            #pragma unroll
            for (int mt = 0; mt < 2; ++mt)
                #pragma unroll
                for (int r = 0; r < 4; ++r) {
                    const int row = 32 * mp + 16 * mt + g * 4 + r;
                    if (row < NTOK) og[row * DIMC + cg] = acc[mt][r];
                }
        }
    }
}

// ================= fallback (512-thread), MODE 0/1 =================
template <int MODE>
__global__ __launch_bounds__(512, 2) void win_attn_kernel(
    const float* __restrict__ x_g,
    const float* __restrict__ mask_g,
    const float* __restrict__ rpb_g,
    const int* __restrict__ rel_g,
    const float* __restrict__ qkvw_g,
    const float* __restrict__ qkvb_g,
    const float* __restrict__ projw_g,
    const float* __restrict__ projb_g,
    const ushort_t* __restrict__ wbf_g,
    float* __restrict__ out_g)
{
    extern __shared__ char smem[];
    ushort_t* x_lds  = (ushort_t*)(smem + FOFF_X);
    ushort_t* q_lds  = (ushort_t*)(smem + FOFF_Q);
    ushort_t* k_lds  = (ushort_t*)(smem + FOFF_K);
    ushort_t* vT     = (ushort_t*)(smem + FOFF_VT);
    ushort_t* P_lds  = (ushort_t*)(smem + FOFF_P);
    float*    mask_p = (float*)(smem + FOFF_MASK);
    float*    rpb_l  = (float*)(smem + FOFF_RPB);
    ushort_t* rel_p  = (ushort_t*)(smem + FOFF_REL);
    float*    bq     = (float*)(smem + FOFF_BQ);
    float*    bp     = (float*)(smem + FOFF_BP);

    const int tid  = threadIdx.x;
    const int b    = blockIdx.x;
    const int wi   = b & 63;
    const int w    = tid >> 6;
    const int lane = tid & 63;
    const int g    = lane >> 4;
    const int c    = lane & 15;

    bf16x8 ring[4][6];
    if constexpr (MODE >= 1) {
        const int cq = w & 3;
        const ushort_t* wq = wbf_g + (size_t)cq * (9 * 6 * 64 * 8);
        #pragma unroll
        for (int p = 0; p < 3; ++p)
            #pragma unroll
            for (int kk = 0; kk < 6; ++kk)
                ring[p][kk] = *(const bf16x8*)(wq + (size_t)((p * 6 + kk) * 64 + lane) * 8);
        __builtin_amdgcn_sched_barrier(0);
    }

    {
        const float* xg = x_g + (size_t)b * (NTOK * DIMC);
        for (int i = tid; i < 64 * 24; i += 512) {
            int row = i / 24, col = (i % 24) * 8;
            u32x4 v = {0u, 0u, 0u, 0u};
            if (row < NTOK) {
                const float* src = xg + row * DIMC + col;
                f32x4 a = *(const f32x4*)src;
                f32x4 d = *(const f32x4*)(src + 4);
                v[0] = cvtpk(a[0], a[1]); v[1] = cvtpk(a[2], a[3]);
                v[2] = cvtpk(d[0], d[1]); v[3] = cvtpk(d[2], d[3]);
            }
            *(u32x4*)&x_lds[row * XS + col] = v;
        }
        const float* mw = mask_g + (size_t)wi * (NTOK * NTOK);
        for (int i = tid; i < 64 * 64; i += 512) {
            int m = i >> 6, n = i & 63;
            float f;
            if (n >= NTOK)      f = -30000.0f;
            else if (m >= NTOK) f = 0.0f;
            else                f = mw[m * NTOK + n];
            mask_p[m * MS + n] = f;
            rel_p[m * RS + n] = (m < NTOK && n < NTOK) ? (ushort_t)rel_g[m * NTOK + n]
                                                       : (ushort_t)0;
        }
        for (int i = tid; i < 169 * 6; i += 512)
            rpb_l[(i / 6) * 8 + (i % 6)] = rpb_g[i];
        for (int i = tid; i < 576; i += 512) {
            float v = qkvb_g[i];
            if constexpr (MODE >= 1) { if (i < 192) v *= SCALE * LOG2E; }
            bq[i] = v;
        }
        if (tid < 192) bp[tid] = projb_g[tid];
    }
    __syncthreads();

    {
        const int mh = w >> 2, cq = w & 3;
        const ushort_t* wq = wbf_g + (size_t)cq * (9 * 6 * 64 * 8);
        bf16x8 ax[2][6];
        #pragma unroll
        for (int mt = 0; mt < 2; ++mt)
            #pragma unroll
            for (int kk = 0; kk < 6; ++kk)
                ax[mt][kk] = *(const bf16x8*)&x_lds[(32 * mh + 16 * mt + c) * XS + kk * 32 + g * 8];

        #pragma unroll
        for (int nt = 0; nt < 9; ++nt) {
            const int cg = 144 * cq + nt * 16 + c;
            bf16x8 bw[6];
            if constexpr (MODE >= 1) {
                if (nt + 3 < 9) {
                    #pragma unroll
                    for (int kk = 0; kk < 6; ++kk)
                        ring[(nt + 3) & 3][kk] =
                            *(const bf16x8*)(wq + (size_t)(((nt + 3) * 6 + kk) * 64 + lane) * 8);
                }
                __builtin_amdgcn_sched_barrier(0);
                #pragma unroll
                for (int kk = 0; kk < 6; ++kk) bw[kk] = ring[nt & 3][kk];
            } else {
                #pragma unroll
                for (int kk = 0; kk < 6; ++kk)
                    bw[kk] = cvt8(qkvw_g + (size_t)cg * DIMC + kk * 32 + g * 8);
            }
            const float bias = bq[cg];
            f32x4 acc[2];
            acc[0] = (f32x4){bias, bias, bias, bias};
            acc[1] = acc[0];
            #pragma unroll
            for (int kk = 0; kk < 6; ++kk)
                #pragma unroll
                for (int mt = 0; mt < 2; ++mt)
                    acc[mt] = __builtin_amdgcn_mfma_f32_16x16x32_bf16(ax[mt][kk], bw[kk], acc[mt], 0, 0, 0);

            const int seg = 144 * cq + nt * 16;
            if (seg < 192) {
                #pragma unroll
                for (int mt = 0; mt < 2; ++mt) {
                    uint32_t p01 = cvtpk(acc[mt][0], acc[mt][1]);
                    uint32_t p23 = cvtpk(acc[mt][2], acc[mt][3]);
                    const int r0 = 32 * mh + 16 * mt + g * 4;
                    q_lds[(r0 + 0) * XS + cg] = (ushort_t)p01;
                    q_lds[(r0 + 1) * XS + cg] = (ushort_t)(p01 >> 16);
                    q_lds[(r0 + 2) * XS + cg] = (ushort_t)p23;
                    q_lds[(r0 + 3) * XS + cg] = (ushort_t)(p23 >> 16);
                }
            } else if (seg < 384) {
                const int ck = cg - 192;
                #pragma unroll
                for (int mt = 0; mt < 2; ++mt) {
                    uint32_t p01 = cvtpk(acc[mt][0], acc[mt][1]);
                    uint32_t p23 = cvtpk(acc[mt][2], acc[mt][3]);
                    const int r0 = 32 * mh + 16 * mt + g * 4;
                    k_lds[(r0 + 0) * XS + ck] = (ushort_t)p01;
                    k_lds[(r0 + 1) * XS + ck] = (ushort_t)(p01 >> 16);
                    k_lds[(r0 + 2) * XS + ck] = (ushort_t)p23;
                    k_lds[(r0 + 3) * XS + ck] = (ushort_t)(p23 >> 16);
                }
            } else {
                const int cv = cg - 384;
                #pragma unroll
                for (int mt = 0; mt < 2; ++mt) {
                    uint32_t* dst = (uint32_t*)&vT[cv * VTS + 32 * mh + 16 * mt + g * 4];
                    dst[0] = cvtpk(acc[mt][0], acc[mt][1]);
                    dst[1] = cvtpk(acc[mt][2], acc[mt][3]);
                }
            }
        }
    }
    __syncthreads();

    bf16x8 pw[3][6];
    {
        const int wsid = w & 3, hh = w >> 2;
        ushort_t* Pw = P_lds + w * (16 * PS);
        const int mq0 = 16 * wsid + g * 4;
        auto head = [&](int h) {
            bf16x8 aq = *(const bf16x8*)&q_lds[(16 * wsid + c) * XS + h * HD + g * 8];
            f32x4 S[4];
            #pragma unroll
            for (int t = 0; t < 4; ++t) {
                bf16x8 bk = *(const bf16x8*)&k_lds[(16 * t + c) * XS + h * HD + g * 8];
                f32x4 z = {0.f, 0.f, 0.f, 0.f};
                S[t] = __builtin_amdgcn_mfma_f32_16x16x32_bf16(aq, bk, z, 0, 0, 0);
            }
            float rinv[4];
            #pragma unroll
            for (int r = 0; r < 4; ++r) {
                const int mq = mq0 + r;
                const float*    mrow = mask_p + mq * MS;
                const ushort_t* rrow = rel_p + mq * RS;
                float sv[4];
                #pragma unroll
                for (int t = 0; t < 4; ++t) {
                    const int n = 16 * t + c;
                    float sc = (MODE == 0) ? SCALE : 0.6931471805599453f;
                    sv[t] = S[t][r] * sc + rpb_l[(int)rrow[n] * 8 + h] + mrow[n];
                }
                float vmax = fmaxf(fmaxf(sv[0], sv[1]), fmaxf(sv[2], sv[3]));
                #pragma unroll
                for (int xm = 1; xm < 16; xm <<= 1)
                    vmax = fmaxf(vmax, __shfl_xor(vmax, xm));
                float sum = 0.f;
                float ev[4];
                #pragma unroll
                for (int t = 0; t < 4; ++t) {
                    ev[t] = __expf(fmaxf(sv[t] - vmax, -80.0f));
                    sum += ev[t];
                }
                #pragma unroll
                for (int xm = 1; xm < 16; xm <<= 1)
                    sum += __shfl_xor(sum, xm);
                rinv[r] = 1.0f / sum;
                uint32_t p01 = cvtpk(ev[0], ev[1]);
                uint32_t p23 = cvtpk(ev[2], ev[3]);
                ushort_t* pr = Pw + (g * 4 + r) * PS + c;
                pr[0]  = (ushort_t)p01;
                pr[16] = (ushort_t)(p01 >> 16);
                pr[32] = (ushort_t)p23;
                pr[48] = (ushort_t)(p23 >> 16);
            }
            f32x4 z = {0.f, 0.f, 0.f, 0.f};
            f32x4 O[2] = {z, z};
            #pragma unroll
            for (int ks = 0; ks < 2; ++ks) {
                bf16x8 ap = *(const bf16x8*)&Pw[c * PS + ks * 32 + g * 8];
                #pragma unroll
                for (int nt = 0; nt < 2; ++nt) {
                    bf16x8 bv = *(const bf16x8*)&vT[(h * HD + nt * 16 + c) * VTS + ks * 32 + g * 8];
                    O[nt] = __builtin_amdgcn_mfma_f32_16x16x32_bf16(ap, bv, O[nt], 0, 0, 0);
                }
            }
            #pragma unroll
            for (int r = 0; r < 4; ++r) {
                uint32_t po = cvtpk(O[0][r] * rinv[r], O[1][r] * rinv[r]);
                ushort_t* ar = x_lds + (16 * wsid + g * 4 + r) * XS + h * HD + c;
                ar[0]  = (ushort_t)po;
                ar[16] = (ushort_t)(po >> 16);
            }
        };
        head(hh * 3 + 0);
        head(hh * 3 + 1);
        if constexpr (MODE >= 1) {
            const int cq4 = w & 3;
            const ushort_t* wp = wbf_g + QKVW_N + (size_t)cq4 * (3 * 6 * 64 * 8);
            #pragma unroll
            for (int nt = 0; nt < 3; ++nt)
                #pragma unroll
                for (int kk = 0; kk < 6; ++kk)
                    pw[nt][kk] = *(const bf16x8*)(wp + (size_t)((nt * 6 + kk) * 64 + lane) * 8);
            __builtin_amdgcn_sched_barrier(0);
        }
        head(hh * 3 + 2);
    }
    __syncthreads();

    {
        const int mh = w >> 2, cq4 = w & 3;
        bf16x8 aa[2][6];
        #pragma unroll
        for (int mt = 0; mt < 2; ++mt)
            #pragma unroll
            for (int kk = 0; kk < 6; ++kk)
                aa[mt][kk] = *(const bf16x8*)&x_lds[(32 * mh + 16 * mt + c) * XS + kk * 32 + g * 8];

        float* og = out_g + (size_t)b * (NTOK * DIMC);
        #pragma unroll
        for (int nt = 0; nt < 3; ++nt) {
            const int cg = 48 * cq4 + nt * 16 + c;
            bf16x8 bw[6];
            #pragma unroll
            for (int kk = 0; kk < 6; ++kk) {
                if constexpr (MODE >= 1)
                    bw[kk] = pw[nt][kk];
                else
                    bw[kk] = cvt8(projw_g + (size_t)cg * DIMC + kk * 32 + g * 8);
            }
            const float bias = bp[cg];
            f32x4 acc[2];
            acc[0] = (f32x4){bias, bias, bias, bias};
            acc[1] = acc[0];
            #pragma unroll
            for (int kk = 0; kk < 6; ++kk)
                #pragma unroll
                for (int mt = 0; mt < 2; ++mt)
                    acc[mt] = __builtin_amdgcn_mfma_f32_16x16x32_bf16(aa[mt][kk], bw[kk], acc[mt], 0, 0, 0);
            #pragma unroll
            for (int mt = 0; mt < 2; ++mt)
                #pragma unroll
                for (int r = 0; r < 4; ++r) {
                    const int row = 32 * mh + 16 * mt + g * 4 + r;
                    if (row < NTOK) og[row * DIMC + cg] = acc[mt][r];
                }
        }
    }
}

extern "C" void kernel_launch(void* const* d_in, const int* in_sizes, int n_in,
                              void* d_out, int out_size, void* d_ws, size_t ws_size,
                              hipStream_t stream) {
    (void)in_sizes; (void)n_in; (void)out_size;
    const float* x_g     = (const float*)d_in[0];
    const float* mask_g  = (const float*)d_in[1];
    const float* rpb_g   = (const float*)d_in[2];
    const int*   rel_g   = (const int*)d_in[3];
    const float* qkvw_g  = (const float*)d_in[4];
    const float* qkvb_g  = (const float*)d_in[5];
    const float* projw_g = (const float*)d_in[6];
    const float* projb_g = (const float*)d_in[7];
    float*       out_g   = (float*)d_out;

    const bool has_w = (d_ws != nullptr) && (ws_size >= WS_NEED1);
    const bool has_b = (d_ws != nullptr) && (ws_size >= WS_NEED2);
    ushort_t* wbf = (ushort_t*)d_ws;
    float* bias4 = (float*)((char*)d_ws + WBF_BYTES);

    if (has_w) {
        int ngrp = QKV_GRP + PROJ_GRP;
        hipLaunchKernelGGL(swz_weights_kernel, dim3((ngrp + 255) / 256), dim3(256), 0, stream,
                           qkvw_g, projw_g, wbf);
    }
    if (has_b) {
        int nthr = BIAS_FLOATS / 4;
        hipLaunchKernelGGL(bias_kernel, dim3((nthr + 255) / 256), dim3(256), 0, stream,
                           mask_g, rpb_g, rel_g, bias4);
        hipFuncSetAttribute((const void*)win_attn12_kernel,
                            hipFuncAttributeMaxDynamicSharedMemorySize, SMEM12);
        hipLaunchKernelGGL(win_attn12_kernel, dim3(4096), dim3(768), SMEM12, stream,
                           x_g, qkvb_g, projb_g, wbf, bias4, out_g);
    } else if (has_w) {
        hipFuncSetAttribute((const void*)win_attn_kernel<1>,
                            hipFuncAttributeMaxDynamicSharedMemorySize, FSMEM);
        hipLaunchKernelGGL(win_attn_kernel<1>, dim3(4096), dim3(512), FSMEM, stream,
                           x_g, mask_g, rpb_g, rel_g, qkvw_g, qkvb_g, projw_g, projb_g,
                           wbf, out_g);
    } else {
        hipFuncSetAttribute((const void*)win_attn_kernel<0>,
                            hipFuncAttributeMaxDynamicSharedMemorySize, FSMEM);
        hipLaunchKernelGGL(win_attn_kernel<0>, dim3(4096), dim3(512), FSMEM, stream,
                           x_g, mask_g, rpb_g, rel_g, qkvw_g, qkvb_g, projw_g, projb_g,
                           (const ushort_t*)nullptr, out_g);
    }
}